// Round 1
// baseline (2727.288 us; speedup 1.0000x reference)
//
#include <hip/hip_runtime.h>

#define NROWS 4096
#define MKEYS 4096
#define DDIM  64
#define HSTEP 0.125f
#define SIG0  0.001f
#define NEGBIG (-1.0e30f)

// ---------------------------------------------------------------------------
// x0sq[m] = sum_d x0[m][d]^2
// ---------------------------------------------------------------------------
__global__ __launch_bounds__(256) void x0sq_kernel(const float* __restrict__ x0,
                                                   float* __restrict__ x0sq) {
    int m = blockIdx.x * 256 + threadIdx.x;
    const float4* p = (const float4*)(x0 + (size_t)m * DDIM);
    float s = 0.f;
#pragma unroll
    for (int i = 0; i < 16; ++i) {
        float4 v = p[i];
        s += v.x * v.x + v.y * v.y + v.z * v.z + v.w * v.w;
    }
    x0sq[m] = s;
}

// ---------------------------------------------------------------------------
// G pass: x = src1 + c2*src2 (row-wise), then
//   s[n,m] = scale * <x_n, x0_m> - beta * x0sq[m]
//   w = softmax_m(s);  qt = w @ x0
//   Gout[n] = ((1-SIG0) * x_n - qt_n) * inv_sig
// Block: 256 threads = 4 waves; each wave handles 2 rows. Grid: 4096/8 = 512.
// Lane d owns output dim d (D == wavefront size == 64).
// ---------------------------------------------------------------------------
__global__ __launch_bounds__(256, 2) void g_kernel(
    const float* __restrict__ src1, const float* __restrict__ src2, float c2,
    const float* __restrict__ x0, const float* __restrict__ x0sq,
    float scale, float beta, float inv_sig, float* __restrict__ Gout)
{
    __shared__ float x0t[64][65];     // stride 65: gcd(65,32)=1 -> conflict-free col reads
    __shared__ float pbuf[4][2][64];  // per-wave, per-row softmax weights for this tile

    const int tid  = threadIdx.x;
    const int w    = tid >> 6;
    const int lane = tid & 63;
    const int row0 = blockIdx.x * 8 + w * 2;
    const int row1 = row0 + 1;

    // x rows in registers (every lane holds the full 64-dim row)
    float4 xr0[16], xr1[16];
    {
        const float4* a0 = (const float4*)(src1 + (size_t)row0 * DDIM);
        const float4* b0 = (const float4*)(src2 + (size_t)row0 * DDIM);
        const float4* a1 = (const float4*)(src1 + (size_t)row1 * DDIM);
        const float4* b1 = (const float4*)(src2 + (size_t)row1 * DDIM);
#pragma unroll
        for (int i = 0; i < 16; ++i) {
            float4 a = a0[i], b = b0[i];
            xr0[i] = make_float4(a.x + c2 * b.x, a.y + c2 * b.y,
                                 a.z + c2 * b.z, a.w + c2 * b.w);
            a = a1[i]; b = b1[i];
            xr1[i] = make_float4(a.x + c2 * b.x, a.y + c2 * b.y,
                                 a.z + c2 * b.z, a.w + c2 * b.w);
        }
    }

    float m0 = NEGBIG, m1 = NEGBIG;   // running max
    float l0 = 0.f, l1 = 0.f;         // running denom
    float o0 = 0.f, o1 = 0.f;         // running numerator, dim = lane

    const int sr = tid >> 2, sq_ = tid & 3;  // staging: 4 threads per key row

    for (int tile = 0; tile < MKEYS / 64; ++tile) {
        __syncthreads();  // prev-tile P3 done: safe to overwrite x0t / pbuf
        // ---- stage x0 tile -> LDS (scalar writes, conflict-benign) ----
        {
            const float4* gsrc =
                (const float4*)(x0 + (size_t)(tile * 64 + sr) * DDIM + sq_ * 16);
#pragma unroll
            for (int k = 0; k < 4; ++k) {
                float4 v = gsrc[k];
                int c = sq_ * 16 + k * 4;
                x0t[sr][c + 0] = v.x; x0t[sr][c + 1] = v.y;
                x0t[sr][c + 2] = v.z; x0t[sr][c + 3] = v.w;
            }
        }
        float sqv = x0sq[tile * 64 + lane];

        // ---- P1: scores, key = tile*64+lane, x0 row streamed from L2 ----
        float cr0 = 0.f, cr1 = 0.f;
        {
            const float4* kp = (const float4*)(x0 + (size_t)(tile * 64 + lane) * DDIM);
#pragma unroll
            for (int i = 0; i < 16; ++i) {
                float4 v = kp[i];
                cr0 += xr0[i].x * v.x + xr0[i].y * v.y + xr0[i].z * v.z + xr0[i].w * v.w;
                cr1 += xr1[i].x * v.x + xr1[i].y * v.y + xr1[i].z * v.z + xr1[i].w * v.w;
            }
        }
        float s0 = scale * cr0 - beta * sqv;
        float s1 = scale * cr1 - beta * sqv;

        // ---- P2: online softmax update ----
        float t0 = s0, t1 = s1;
#pragma unroll
        for (int off = 32; off; off >>= 1) {
            t0 = fmaxf(t0, __shfl_xor(t0, off, 64));
            t1 = fmaxf(t1, __shfl_xor(t1, off, 64));
        }
        float mn0 = fmaxf(m0, t0), mn1 = fmaxf(m1, t1);
        float co0 = __expf(m0 - mn0), co1 = __expf(m1 - mn1);
        float p0  = __expf(s0 - mn0), p1  = __expf(s1 - mn1);
        float ps0 = p0, ps1 = p1;
#pragma unroll
        for (int off = 32; off; off >>= 1) {
            ps0 += __shfl_xor(ps0, off, 64);
            ps1 += __shfl_xor(ps1, off, 64);
        }
        l0 = l0 * co0 + ps0;  l1 = l1 * co1 + ps1;
        o0 *= co0;            o1 *= co1;
        m0 = mn0;             m1 = mn1;
        pbuf[w][0][lane] = p0;
        pbuf[w][1][lane] = p1;
        __syncthreads();  // x0t staged + pbuf visible

        // ---- P3: O[lane] += sum_k p[k] * x0t[k][lane] ----
#pragma unroll
        for (int k4 = 0; k4 < 16; ++k4) {
            float4 pa = *(const float4*)&pbuf[w][0][k4 * 4];
            float4 pb = *(const float4*)&pbuf[w][1][k4 * 4];
            int kb = k4 * 4;
            float v0 = x0t[kb + 0][lane];
            float v1 = x0t[kb + 1][lane];
            float v2 = x0t[kb + 2][lane];
            float v3 = x0t[kb + 3][lane];
            o0 += pa.x * v0; o0 += pa.y * v1; o0 += pa.z * v2; o0 += pa.w * v3;
            o1 += pb.x * v0; o1 += pb.y * v1; o1 += pb.z * v2; o1 += pb.w * v3;
        }
    }

    // ---- epilogue ----
    float qt0 = o0 / l0, qt1 = o1 / l1;
    {
        size_t i0 = (size_t)row0 * DDIM + lane;
        size_t i1 = (size_t)row1 * DDIM + lane;
        float xv0 = src1[i0] + c2 * src2[i0];
        float xv1 = src1[i1] + c2 * src2[i1];
        Gout[i0] = ((1.0f - SIG0) * xv0 - qt0) * inv_sig;
        Gout[i1] = ((1.0f - SIG0) * xv1 - qt1) * inv_sig;
    }
}

// ---------------------------------------------------------------------------
// Heun update: xt -= (G1+G2) * (H/2)
// ---------------------------------------------------------------------------
__global__ __launch_bounds__(256) void update_kernel(float* __restrict__ xt,
                                                     const float* __restrict__ G1,
                                                     const float* __restrict__ G2) {
    int i = blockIdx.x * 256 + threadIdx.x;
    xt[i] -= (G1[i] + G2[i]) * (HSTEP * 0.5f);
}

// ---------------------------------------------------------------------------
extern "C" void kernel_launch(void* const* d_in, const int* in_sizes, int n_in,
                              void* d_out, int out_size, void* d_ws, size_t ws_size,
                              hipStream_t stream) {
    const float* z  = (const float*)d_in[0];
    const float* x0 = (const float*)d_in[1];
    float* xt   = (float*)d_out;                 // xt lives in d_out
    float* G1   = (float*)d_ws;
    float* G2   = G1 + (size_t)NROWS * DDIM;
    float* x0sq = G2 + (size_t)NROWS * DDIM;

    // xt = z ; x0sq precompute
    hipMemcpyAsync(xt, z, (size_t)NROWS * DDIM * sizeof(float),
                   hipMemcpyDeviceToDevice, stream);
    x0sq_kernel<<<MKEYS / 256, 256, 0, stream>>>(x0, x0sq);

    // G1 = G(t=1, z): alpha=0, sigma=1 -> scale=0, beta=0 (uniform softmax)
    g_kernel<<<NROWS / 8, 256, 0, stream>>>(xt, xt, 0.0f, x0, x0sq,
                                            0.0f, 0.0f, 1.0f, G1);

    for (int i = 0; i < 7; ++i) {
        float t  = (float)(7 - i) / 8.0f;
        float al = 1.0f - t;
        float sg = SIG0 + (1.0f - SIG0) * t;
        float scale = al / (sg * sg);
        float beta  = al * al / (2.0f * sg * sg);
        // G2 = G(t, xt - H*G1)
        g_kernel<<<NROWS / 8, 256, 0, stream>>>(xt, G1, -HSTEP, x0, x0sq,
                                                scale, beta, 1.0f / sg, G2);
        // xt -= (G1+G2)*(H/2)
        update_kernel<<<(NROWS * DDIM) / 256, 256, 0, stream>>>(xt, G1, G2);
        float* tmp = G1; G1 = G2; G2 = tmp;
    }
}

// Round 2
// 596.838 us; speedup vs baseline: 4.5696x; 4.5696x over previous
//
#include <hip/hip_runtime.h>
#include <hip/hip_bf16.h>

typedef short  short8  __attribute__((ext_vector_type(8)));
typedef float  float4v __attribute__((ext_vector_type(4)));

#define N_ROWS 4096
#define DDIM   64
#define HSTEP  0.125f
#define SIG0   0.001f

__device__ __forceinline__ ushort f2bf(float f) {
    __hip_bfloat16 h = __float2bfloat16(f);
    return *reinterpret_cast<ushort*>(&h);
}
__device__ __forceinline__ float bf2f(ushort u) {
    return __uint_as_float(((unsigned)u) << 16);
}
__device__ __forceinline__ float4v mfma16(short8 a, short8 b, float4v c) {
    return __builtin_amdgcn_mfma_f32_16x16x32_bf16(a, b, c, 0, 0, 0);
}

// ---------------------------------------------------------------------------
// prep: x0 -> x0_hi/lo [4096][64], x0T_hi/lo [64][4096], x0sq[4096], colsum[64]
// ---------------------------------------------------------------------------
__global__ __launch_bounds__(256) void prep_x0_kernel(
    const float* __restrict__ x0, ushort* __restrict__ x0h, ushort* __restrict__ x0l,
    ushort* __restrict__ x0Th, ushort* __restrict__ x0Tl,
    float* __restrict__ x0sq, float* __restrict__ x0sum)
{
    __shared__ float cs[64];
    const int tid = threadIdx.x;
    if (tid < 64) cs[tid] = 0.f;
    __syncthreads();
    const int r  = blockIdx.x * 64 + (tid >> 2);
    const int c0 = (tid & 3) * 16;
    const float* rp = x0 + (size_t)r * DDIM + c0;
    float f[16]; ushort hh[16], ll[16];
    float ss = 0.f;
#pragma unroll
    for (int j = 0; j < 16; ++j) {
        float v = rp[j]; f[j] = v; ss += v * v;
        ushort h = f2bf(v); hh[j] = h;
        ll[j] = f2bf(v - bf2f(h));
        x0Th[(size_t)(c0 + j) * N_ROWS + r] = h;
        x0Tl[(size_t)(c0 + j) * N_ROWS + r] = ll[j];
    }
    uint dwh[8], dwl[8];
#pragma unroll
    for (int j2 = 0; j2 < 8; ++j2) {
        dwh[j2] = (uint)hh[2 * j2] | ((uint)hh[2 * j2 + 1] << 16);
        dwl[j2] = (uint)ll[2 * j2] | ((uint)ll[2 * j2 + 1] << 16);
    }
    uint* ph = (uint*)(x0h + (size_t)r * DDIM + c0);
    uint* pl = (uint*)(x0l + (size_t)r * DDIM + c0);
#pragma unroll
    for (int j2 = 0; j2 < 8; ++j2) { ph[j2] = dwh[j2]; pl[j2] = dwl[j2]; }
    // x0sq: reduce across the 4 lanes sharing a row
    ss += __shfl_xor(ss, 1, 64);
    ss += __shfl_xor(ss, 2, 64);
    if ((tid & 3) == 0) x0sq[r] = ss;
    // column sums for mean(x0)
#pragma unroll
    for (int j = 0; j < 16; ++j) atomicAdd(&cs[c0 + j], f[j]);
    __syncthreads();
    if (tid < 64) atomicAdd(&x0sum[tid], cs[tid]);
}

// ---------------------------------------------------------------------------
// G(t=1) closed form: scores are exactly 0 -> qt = mean(x0); sigma=1
// ---------------------------------------------------------------------------
__global__ __launch_bounds__(256) void g1_init_kernel(
    const float* __restrict__ z, const float* __restrict__ x0sum,
    float* __restrict__ G1)
{
    int i = blockIdx.x * 256 + threadIdx.x;
    G1[i] = (1.0f - SIG0) * z[i] - x0sum[i & 63] * (1.0f / 4096.0f);
}

// ---------------------------------------------------------------------------
// Flash partial pass. Block = 4 waves; wave owns 16 query rows.
// x = src1 + c2*src2 (split hi/lo bf16). Scores via swapped mfma(x0,k=d; x^T):
//   D[key][q], key = ks*16 + (lane>>4)*4 + r, q = lane&15.
// Split-precision: hi*hi + lo*hi + hi*lo. PV: P split hi/lo, in-register
// shfl relayout to A-frag; B = x0T rows from global (L2-resident).
// Partials (o unnormalized, m, l) to workspace; grid.y = key-split.
// ---------------------------------------------------------------------------
__global__ __launch_bounds__(256, 2) void g_partial_kernel(
    const float* __restrict__ src1, const float* __restrict__ src2, float c2,
    const ushort* __restrict__ x0h, const ushort* __restrict__ x0l,
    const ushort* __restrict__ x0Th, const ushort* __restrict__ x0Tl,
    const float* __restrict__ x0sq, float scale, float beta,
    float* __restrict__ o_part, float* __restrict__ m_part,
    float* __restrict__ l_part, int ntiles)
{
    const int tid  = threadIdx.x;
    const int w    = tid >> 6;
    const int lane = tid & 63;
    const int g    = lane >> 4;
    const int qi   = lane & 15;
    const int row  = blockIdx.x * 64 + w * 16 + qi;
    const int split = blockIdx.y;
    const int kb0  = split * (ntiles * 64);

    // ---- x B-frags for this lane's query row: d = dstep*32 + g*8 + j ----
    short8 xbh[2], xbl[2];
    {
        const float* a = src1 + (size_t)row * DDIM;
        const float* b = src2 + (size_t)row * DDIM;
#pragma unroll
        for (int ds_ = 0; ds_ < 2; ++ds_) {
            const int d0 = ds_ * 32 + g * 8;
#pragma unroll
            for (int j = 0; j < 8; ++j) {
                float x = a[d0 + j] + c2 * b[d0 + j];
                ushort h = f2bf(x);
                xbh[ds_][j] = (short)h;
                xbl[ds_][j] = (short)f2bf(x - bf2f(h));
            }
        }
    }

    float4v pvacc[4];
#pragma unroll
    for (int d = 0; d < 4; ++d) pvacc[d] = (float4v){0.f, 0.f, 0.f, 0.f};
    float m = -1.0e30f, lsum = 0.f;

    for (int tile = 0; tile < ntiles; ++tile) {
        const int kb = kb0 + tile * 64;

        // ---- QK^T: scores sc[ks][r], key = kb + ks*16 + g*4 + r ----
        float sc[4][4];
#pragma unroll
        for (int ks = 0; ks < 4; ++ks) {
            const ushort* ar = x0h + (size_t)(kb + ks * 16 + qi) * DDIM + g * 8;
            const ushort* al = x0l + (size_t)(kb + ks * 16 + qi) * DDIM + g * 8;
            short8 Ah0 = *(const short8*)(ar);
            short8 Ah1 = *(const short8*)(ar + 32);
            short8 Al0 = *(const short8*)(al);
            short8 Al1 = *(const short8*)(al + 32);
            float4v acc = (float4v){0.f, 0.f, 0.f, 0.f};
            acc = mfma16(Ah0, xbh[0], acc);
            acc = mfma16(Ah1, xbh[1], acc);
            acc = mfma16(Al0, xbh[0], acc);
            acc = mfma16(Al1, xbh[1], acc);
            acc = mfma16(Ah0, xbl[0], acc);
            acc = mfma16(Ah1, xbl[1], acc);
            const float4 sq = *(const float4*)(x0sq + kb + ks * 16 + g * 4);
            sc[ks][0] = scale * acc[0] - beta * sq.x;
            sc[ks][1] = scale * acc[1] - beta * sq.y;
            sc[ks][2] = scale * acc[2] - beta * sq.z;
            sc[ks][3] = scale * acc[3] - beta * sq.w;
        }

        // ---- online softmax ----
        float tmax = sc[0][0];
#pragma unroll
        for (int ks = 0; ks < 4; ++ks)
#pragma unroll
            for (int r = 0; r < 4; ++r) tmax = fmaxf(tmax, sc[ks][r]);
        tmax = fmaxf(tmax, __shfl_xor(tmax, 16, 64));
        tmax = fmaxf(tmax, __shfl_xor(tmax, 32, 64));
        const float mn = fmaxf(m, tmax);
        const float co = __expf(m - mn);
        float p[4][4];
        float psum = 0.f;
#pragma unroll
        for (int ks = 0; ks < 4; ++ks)
#pragma unroll
            for (int r = 0; r < 4; ++r) {
                p[ks][r] = __expf(sc[ks][r] - mn);
                psum += p[ks][r];
            }
        psum += __shfl_xor(psum, 16, 64);
        psum += __shfl_xor(psum, 32, 64);
        lsum = lsum * co + psum;
        m = mn;
        // rescale PV accumulators (acc row = q_local = g*4 + r)
        float co_r[4];
#pragma unroll
        for (int r = 0; r < 4; ++r) co_r[r] = __shfl(co, g * 4 + r, 64);
#pragma unroll
        for (int d = 0; d < 4; ++d)
#pragma unroll
            for (int r = 0; r < 4; ++r) pvacc[d][r] *= co_r[r];

        // ---- pack P hi/lo into dwords: pk[ks][pr] = keys (ks*16+g*4+2pr, +1) ----
        uint pkh[4][2], pkl[4][2];
#pragma unroll
        for (int ks = 0; ks < 4; ++ks)
#pragma unroll
            for (int pr = 0; pr < 2; ++pr) {
                float f0 = p[ks][2 * pr], f1 = p[ks][2 * pr + 1];
                ushort h0 = f2bf(f0), h1 = f2bf(f1);
                pkh[ks][pr] = (uint)h0 | ((uint)h1 << 16);
                ushort e0 = f2bf(f0 - bf2f(h0)), e1 = f2bf(f1 - bf2f(h1));
                pkl[ks][pr] = (uint)e0 | ((uint)e1 << 16);
            }

        // ---- PV per 32-key step: in-register relayout to A-frag, then MFMA ----
#pragma unroll
        for (int ks2 = 0; ks2 < 2; ++ks2) {
            uint pah[4], pal[4];
#pragma unroll
            for (int c = 0; c < 4; ++c) {
                const int src = (2 * (g & 1) + (c >> 1)) * 16 + qi;
                uint h0 = (uint)__shfl((int)pkh[2 * ks2][c & 1], src, 64);
                uint h1 = (uint)__shfl((int)pkh[2 * ks2 + 1][c & 1], src, 64);
                pah[c] = (g >= 2) ? h1 : h0;
                uint l0 = (uint)__shfl((int)pkl[2 * ks2][c & 1], src, 64);
                uint l1 = (uint)__shfl((int)pkl[2 * ks2 + 1][c & 1], src, 64);
                pal[c] = (g >= 2) ? l1 : l0;
            }
            short8 PAh, PAl;
#pragma unroll
            for (int c = 0; c < 4; ++c) {
                PAh[2 * c]     = (short)(pah[c] & 0xffff);
                PAh[2 * c + 1] = (short)(pah[c] >> 16);
                PAl[2 * c]     = (short)(pal[c] & 0xffff);
                PAl[2 * c + 1] = (short)(pal[c] >> 16);
            }
            const int kk = kb + ks2 * 32 + g * 8;
#pragma unroll
            for (int dsub = 0; dsub < 4; ++dsub) {
                short8 Bh = *(const short8*)(x0Th + (size_t)(dsub * 16 + qi) * N_ROWS + kk);
                short8 Bl = *(const short8*)(x0Tl + (size_t)(dsub * 16 + qi) * N_ROWS + kk);
                pvacc[dsub] = mfma16(PAh, Bh, pvacc[dsub]);
                pvacc[dsub] = mfma16(PAh, Bl, pvacc[dsub]);
                pvacc[dsub] = mfma16(PAl, Bh, pvacc[dsub]);
            }
        }
    }

    // ---- store partials: PV D row = q_local = g*4 + r, col d = dsub*16 + qi ----
    const int orow0 = blockIdx.x * 64 + w * 16;
#pragma unroll
    for (int dsub = 0; dsub < 4; ++dsub)
#pragma unroll
        for (int r = 0; r < 4; ++r)
            o_part[((size_t)split * N_ROWS + orow0 + g * 4 + r) * DDIM + dsub * 16 + qi] =
                pvacc[dsub][r];
    if (g == 0) {
        m_part[split * N_ROWS + orow0 + qi] = m;
        l_part[split * N_ROWS + orow0 + qi] = lsum;
    }
}

// ---------------------------------------------------------------------------
// Combine partials -> qt -> G2; fused Heun update of xt.
// Wave per row, lane = d.
// ---------------------------------------------------------------------------
__global__ __launch_bounds__(256) void combine_kernel(
    float* __restrict__ xt, const float* __restrict__ G1, float c2,
    const float* __restrict__ o_part, const float* __restrict__ m_part,
    const float* __restrict__ l_part, float inv_sig,
    float* __restrict__ G2out, int nsplit)
{
    const int tid = threadIdx.x;
    const int w = tid >> 6, lane = tid & 63;
    const int row = blockIdx.x * 4 + w;
    float mstar = -1.0e30f;
    for (int i = 0; i < nsplit; ++i)
        mstar = fmaxf(mstar, m_part[i * N_ROWS + row]);
    float L = 0.f, num = 0.f;
    for (int i = 0; i < nsplit; ++i) {
        float e = __expf(m_part[i * N_ROWS + row] - mstar);
        L   += l_part[i * N_ROWS + row] * e;
        num += o_part[((size_t)i * N_ROWS + row) * DDIM + lane] * e;
    }
    const float qt = num / L;
    const size_t idx = (size_t)row * DDIM + lane;
    const float g1 = G1[idx];
    const float x  = xt[idx] + c2 * g1;
    const float g2 = ((1.0f - SIG0) * x - qt) * inv_sig;
    G2out[idx] = g2;
    xt[idx] -= (g1 + g2) * (HSTEP * 0.5f);
}

// ---------------------------------------------------------------------------
extern "C" void kernel_launch(void* const* d_in, const int* in_sizes, int n_in,
                              void* d_out, int out_size, void* d_ws, size_t ws_size,
                              hipStream_t stream) {
    const float* z  = (const float*)d_in[0];
    const float* x0 = (const float*)d_in[1];
    float* xt = (float*)d_out;

    // ---- workspace layout (256B aligned blocks) ----
    char* p = (char*)d_ws;
    auto alloc = [&](size_t bytes) {
        char* q = p; p += (bytes + 255) & ~(size_t)255; return q;
    };
    float*  G1    = (float*)alloc((size_t)N_ROWS * DDIM * 4);
    float*  G2    = (float*)alloc((size_t)N_ROWS * DDIM * 4);
    float*  x0sq  = (float*)alloc((size_t)N_ROWS * 4);
    float*  x0sum = (float*)alloc(64 * 4);
    ushort* x0h   = (ushort*)alloc((size_t)N_ROWS * DDIM * 2);
    ushort* x0l   = (ushort*)alloc((size_t)N_ROWS * DDIM * 2);
    ushort* x0Th  = (ushort*)alloc((size_t)N_ROWS * DDIM * 2);
    ushort* x0Tl  = (ushort*)alloc((size_t)N_ROWS * DDIM * 2);
    size_t fixed = (size_t)(p - (char*)d_ws);
    // per-split: o (4096*64 f32) + m,l (4096 f32 each)
    const size_t per_split = ((size_t)N_ROWS * DDIM + 2 * N_ROWS) * 4 + 768;
    int SPLIT = 8;
    while (SPLIT > 1 && fixed + (size_t)SPLIT * per_split > ws_size) SPLIT >>= 1;
    float* o_part = (float*)alloc((size_t)SPLIT * N_ROWS * DDIM * 4);
    float* m_part = (float*)alloc((size_t)SPLIT * N_ROWS * 4);
    float* l_part = (float*)alloc((size_t)SPLIT * N_ROWS * 4);
    const int ntiles = (N_ROWS / 64) / SPLIT;

    // ---- init: xt = z; x0 derived arrays; G1 = G(t=1) closed form ----
    hipMemcpyAsync(xt, z, (size_t)N_ROWS * DDIM * 4, hipMemcpyDeviceToDevice, stream);
    hipMemsetAsync(x0sum, 0, 64 * 4, stream);
    prep_x0_kernel<<<N_ROWS / 64, 256, 0, stream>>>(x0, x0h, x0l, x0Th, x0Tl, x0sq, x0sum);
    g1_init_kernel<<<(N_ROWS * DDIM) / 256, 256, 0, stream>>>(z, x0sum, G1);

    // ---- 7 Heun steps ----
    for (int i = 0; i < 7; ++i) {
        float t  = (float)(7 - i) / 8.0f;
        float al = 1.0f - t;
        float sg = SIG0 + (1.0f - SIG0) * t;
        float scale = al / (sg * sg);
        float beta  = al * al / (2.0f * sg * sg);
        g_partial_kernel<<<dim3(N_ROWS / 64, SPLIT), 256, 0, stream>>>(
            xt, G1, -HSTEP, x0h, x0l, x0Th, x0Tl, x0sq, scale, beta,
            o_part, m_part, l_part, ntiles);
        combine_kernel<<<N_ROWS / 4, 256, 0, stream>>>(
            xt, G1, -HSTEP, o_part, m_part, l_part, 1.0f / sg, G2, SPLIT);
        float* tmp = G1; G1 = G2; G2 = tmp;
    }
}

// Round 3
// 347.411 us; speedup vs baseline: 7.8503x; 1.7180x over previous
//
#include <hip/hip_runtime.h>
#include <hip/hip_bf16.h>

typedef short  short8  __attribute__((ext_vector_type(8)));
typedef float  float4v __attribute__((ext_vector_type(4)));

#define N_ROWS 4096
#define DDIM   64
#define NKB    (N_ROWS / 64)
#define HSTEP  0.125f
#define SIG0   0.001f

__device__ __forceinline__ ushort f2bf(float f) {
    __hip_bfloat16 h = __float2bfloat16(f);
    return *reinterpret_cast<ushort*>(&h);
}
__device__ __forceinline__ float bf2f(ushort u) {
    return __uint_as_float(((unsigned)u) << 16);
}
__device__ __forceinline__ float4v mfma16(short8 a, short8 b, float4v c) {
    return __builtin_amdgcn_mfma_f32_16x16x32_bf16(a, b, c, 0, 0, 0);
}

// ---------------------------------------------------------------------------
// x0 stats: x0sq[m] = ||x0_m||^2, x0sum[d] = sum_m x0[m][d]
// grid 64 blocks x 256 (4 threads per row)
// ---------------------------------------------------------------------------
__global__ __launch_bounds__(256) void x0stats_kernel(
    const float* __restrict__ x0, float* __restrict__ x0sq,
    float* __restrict__ x0sum)
{
    __shared__ float cs[64];
    const int tid = threadIdx.x;
    if (tid < 64) cs[tid] = 0.f;
    __syncthreads();
    const int r  = blockIdx.x * 64 + (tid >> 2);
    const int c0 = (tid & 3) * 16;
    const float4* rp = (const float4*)(x0 + (size_t)r * DDIM + c0);
    float f[16];
    float ss = 0.f;
#pragma unroll
    for (int k = 0; k < 4; ++k) {
        float4 v = rp[k];
        f[4 * k] = v.x; f[4 * k + 1] = v.y; f[4 * k + 2] = v.z; f[4 * k + 3] = v.w;
        ss += v.x * v.x + v.y * v.y + v.z * v.z + v.w * v.w;
    }
    ss += __shfl_xor(ss, 1, 64);
    ss += __shfl_xor(ss, 2, 64);
    if ((tid & 3) == 0) x0sq[r] = ss;
#pragma unroll
    for (int j = 0; j < 16; ++j) atomicAdd(&cs[c0 + j], f[j]);
    __syncthreads();
    if (tid < 64) atomicAdd(&x0sum[tid], cs[tid]);
}

// ---------------------------------------------------------------------------
// Pre-pack x0 into MFMA-fragment order (hi/lo split bf16), one key-block per
// block. Apk[kb][ks][half][lane]: lane(g,qi) holds x0[kb*64+ks*16+qi][half*32+g*8+j].
// Bpk[kb][ks2][dsub][lane]: lane(g,qi) holds x0[kb*64+ks2*32+g*8+j][dsub*16+qi].
// Main-loop loads become fully coalesced 1KB-per-instruction streams.
// ---------------------------------------------------------------------------
__global__ __launch_bounds__(256) void prep_pack_kernel(
    const float* __restrict__ x0,
    short8* __restrict__ Apk_h, short8* __restrict__ Apk_l,
    short8* __restrict__ Bpk_h, short8* __restrict__ Bpk_l)
{
    __shared__ float xt_[64][65];
    const int tid  = threadIdx.x;
    const int kb64 = blockIdx.x;
    {
        const int r = tid >> 2, c0 = (tid & 3) * 16;
        const float4* src = (const float4*)(x0 + ((size_t)(kb64 * 64 + r)) * DDIM + c0);
#pragma unroll
        for (int k = 0; k < 4; ++k) {
            float4 v = src[k];
            xt_[r][c0 + 4 * k + 0] = v.x; xt_[r][c0 + 4 * k + 1] = v.y;
            xt_[r][c0 + 4 * k + 2] = v.z; xt_[r][c0 + 4 * k + 3] = v.w;
        }
    }
    __syncthreads();
    const int w = tid >> 6, lane = tid & 63, qi = lane & 15, g = lane >> 4;
    // A-frags: wave w handles ks = w
#pragma unroll
    for (int half = 0; half < 2; ++half) {
        short8 h, l;
#pragma unroll
        for (int j = 0; j < 8; ++j) {
            float v = xt_[w * 16 + qi][half * 32 + g * 8 + j];
            ushort hh = f2bf(v);
            h[j] = (short)hh;
            l[j] = (short)f2bf(v - bf2f(hh));
        }
        size_t idx = (((size_t)kb64 * 4 + w) * 2 + half) * 64 + lane;
        Apk_h[idx] = h; Apk_l[idx] = l;
    }
    // B-frags: wave w handles (ks2,dsub) = pw, pw+4
#pragma unroll
    for (int pp = 0; pp < 2; ++pp) {
        int pw = w + pp * 4;
        int ks2 = pw >> 2, dsub = pw & 3;
        short8 h, l;
#pragma unroll
        for (int j = 0; j < 8; ++j) {
            float v = xt_[ks2 * 32 + g * 8 + j][dsub * 16 + qi];
            ushort hh = f2bf(v);
            h[j] = (short)hh;
            l[j] = (short)f2bf(v - bf2f(hh));
        }
        size_t idx = (((size_t)kb64 * 2 + ks2) * 4 + dsub) * 64 + lane;
        Bpk_h[idx] = h; Bpk_l[idx] = l;
    }
}

// ---------------------------------------------------------------------------
// G(t=1) closed form: scores are exactly 0 -> qt = mean(x0); sigma=1
// ---------------------------------------------------------------------------
__global__ __launch_bounds__(256) void g1_init_kernel(
    const float* __restrict__ z, const float* __restrict__ x0sum,
    float* __restrict__ G1)
{
    int i = blockIdx.x * 256 + threadIdx.x;
    G1[i] = (1.0f - SIG0) * z[i] - x0sum[i & 63] * (1.0f / 4096.0f);
}

// ---------------------------------------------------------------------------
// Flash partial pass (split-precision bf16 MFMA). Block = 4 waves; wave owns
// 16 query rows; all waves share the key-block fragments (L2/L1-resident,
// coalesced packed loads). grid = (N/64, SPLIT).
// ---------------------------------------------------------------------------
__global__ __launch_bounds__(256, 4) void g_partial_kernel(
    const float* __restrict__ src1, const float* __restrict__ src2, float c2,
    const short8* __restrict__ Apk_h, const short8* __restrict__ Apk_l,
    const short8* __restrict__ Bpk_h, const short8* __restrict__ Bpk_l,
    const float* __restrict__ x0sq, float scale, float beta,
    float* __restrict__ o_part, float* __restrict__ m_part,
    float* __restrict__ l_part, int ntiles)
{
    const int tid  = threadIdx.x;
    const int w    = tid >> 6;
    const int lane = tid & 63;
    const int g    = lane >> 4;
    const int qi   = lane & 15;
    const int row  = blockIdx.x * 64 + w * 16 + qi;
    const int split = blockIdx.y;

    // ---- x B-frags for this lane's query row: d = dstep*32 + g*8 + j ----
    short8 xbh[2], xbl[2];
    {
        const float* a = src1 + (size_t)row * DDIM;
        const float* b = src2 + (size_t)row * DDIM;
#pragma unroll
        for (int ds_ = 0; ds_ < 2; ++ds_) {
            const int d0 = ds_ * 32 + g * 8;
#pragma unroll
            for (int j = 0; j < 8; ++j) {
                float x = a[d0 + j] + c2 * b[d0 + j];
                ushort h = f2bf(x);
                xbh[ds_][j] = (short)h;
                xbl[ds_][j] = (short)f2bf(x - bf2f(h));
            }
        }
    }

    float4v pvacc[4];
#pragma unroll
    for (int d = 0; d < 4; ++d) pvacc[d] = (float4v){0.f, 0.f, 0.f, 0.f};
    float m = -1.0e30f, lsum = 0.f;

    for (int tile = 0; tile < ntiles; ++tile) {
        const int kbi = split * ntiles + tile;   // key-block index
        const int kb  = kbi * 64;

        // ---- QK^T: scores sc[ks][r], key = kb + ks*16 + g*4 + r ----
        float sc[4][4];
#pragma unroll
        for (int ks = 0; ks < 4; ++ks) {
            const size_t ai = (((size_t)kbi * 4 + ks) * 2) * 64 + lane;
            short8 Ah0 = Apk_h[ai];
            short8 Ah1 = Apk_h[ai + 64];
            short8 Al0 = Apk_l[ai];
            short8 Al1 = Apk_l[ai + 64];
            float4v acc = (float4v){0.f, 0.f, 0.f, 0.f};
            acc = mfma16(Ah0, xbh[0], acc);
            acc = mfma16(Ah1, xbh[1], acc);
            acc = mfma16(Al0, xbh[0], acc);
            acc = mfma16(Al1, xbh[1], acc);
            acc = mfma16(Ah0, xbl[0], acc);
            acc = mfma16(Ah1, xbl[1], acc);
            const float4 sq = *(const float4*)(x0sq + kb + ks * 16 + g * 4);
            sc[ks][0] = scale * acc[0] - beta * sq.x;
            sc[ks][1] = scale * acc[1] - beta * sq.y;
            sc[ks][2] = scale * acc[2] - beta * sq.z;
            sc[ks][3] = scale * acc[3] - beta * sq.w;
        }

        // ---- online softmax ----
        float tmax = sc[0][0];
#pragma unroll
        for (int ks = 0; ks < 4; ++ks)
#pragma unroll
            for (int r = 0; r < 4; ++r) tmax = fmaxf(tmax, sc[ks][r]);
        tmax = fmaxf(tmax, __shfl_xor(tmax, 16, 64));
        tmax = fmaxf(tmax, __shfl_xor(tmax, 32, 64));
        const float mn = fmaxf(m, tmax);
        const float co = __expf(m - mn);
        float p[4][4];
        float psum = 0.f;
#pragma unroll
        for (int ks = 0; ks < 4; ++ks)
#pragma unroll
            for (int r = 0; r < 4; ++r) {
                p[ks][r] = __expf(sc[ks][r] - mn);
                psum += p[ks][r];
            }
        psum += __shfl_xor(psum, 16, 64);
        psum += __shfl_xor(psum, 32, 64);
        lsum = lsum * co + psum;
        m = mn;
        float co_r[4];
#pragma unroll
        for (int r = 0; r < 4; ++r) co_r[r] = __shfl(co, g * 4 + r, 64);
#pragma unroll
        for (int d = 0; d < 4; ++d)
#pragma unroll
            for (int r = 0; r < 4; ++r) pvacc[d][r] *= co_r[r];

        // ---- pack P hi/lo into dwords: pk[ks][pr] = keys (ks*16+g*4+2pr, +1) ----
        uint pkh[4][2], pkl[4][2];
#pragma unroll
        for (int ks = 0; ks < 4; ++ks)
#pragma unroll
            for (int pr = 0; pr < 2; ++pr) {
                float f0 = p[ks][2 * pr], f1 = p[ks][2 * pr + 1];
                ushort h0 = f2bf(f0), h1 = f2bf(f1);
                pkh[ks][pr] = (uint)h0 | ((uint)h1 << 16);
                ushort e0 = f2bf(f0 - bf2f(h0)), e1 = f2bf(f1 - bf2f(h1));
                pkl[ks][pr] = (uint)e0 | ((uint)e1 << 16);
            }

        // ---- PV per 32-key step: in-register relayout to A-frag, then MFMA ----
#pragma unroll
        for (int ks2 = 0; ks2 < 2; ++ks2) {
            uint pah[4], pal[4];
#pragma unroll
            for (int c = 0; c < 4; ++c) {
                const int src = (2 * (g & 1) + (c >> 1)) * 16 + qi;
                uint h0 = (uint)__shfl((int)pkh[2 * ks2][c & 1], src, 64);
                uint h1 = (uint)__shfl((int)pkh[2 * ks2 + 1][c & 1], src, 64);
                pah[c] = (g >= 2) ? h1 : h0;
                uint l0 = (uint)__shfl((int)pkl[2 * ks2][c & 1], src, 64);
                uint l1 = (uint)__shfl((int)pkl[2 * ks2 + 1][c & 1], src, 64);
                pal[c] = (g >= 2) ? l1 : l0;
            }
            short8 PAh, PAl;
#pragma unroll
            for (int c = 0; c < 4; ++c) {
                PAh[2 * c]     = (short)(pah[c] & 0xffff);
                PAh[2 * c + 1] = (short)(pah[c] >> 16);
                PAl[2 * c]     = (short)(pal[c] & 0xffff);
                PAl[2 * c + 1] = (short)(pal[c] >> 16);
            }
#pragma unroll
            for (int dsub = 0; dsub < 4; ++dsub) {
                const size_t bi = (((size_t)kbi * 2 + ks2) * 4 + dsub) * 64 + lane;
                short8 Bh = Bpk_h[bi];
                short8 Bl = Bpk_l[bi];
                pvacc[dsub] = mfma16(PAh, Bh, pvacc[dsub]);
                pvacc[dsub] = mfma16(PAh, Bl, pvacc[dsub]);
                pvacc[dsub] = mfma16(PAl, Bh, pvacc[dsub]);
            }
        }
    }

    // ---- store partials: PV D row = q_local = g*4 + r, col d = dsub*16 + qi ----
    const int orow0 = blockIdx.x * 64 + w * 16;
#pragma unroll
    for (int dsub = 0; dsub < 4; ++dsub)
#pragma unroll
        for (int r = 0; r < 4; ++r)
            o_part[((size_t)split * N_ROWS + orow0 + g * 4 + r) * DDIM + dsub * 16 + qi] =
                pvacc[dsub][r];
    if (g == 0) {
        m_part[split * N_ROWS + orow0 + qi] = m;
        l_part[split * N_ROWS + orow0 + qi] = lsum;
    }
}

// ---------------------------------------------------------------------------
// Combine partials -> qt -> G2; fused Heun update of xt. Wave per row, lane=d.
// ---------------------------------------------------------------------------
__global__ __launch_bounds__(256) void combine_kernel(
    float* __restrict__ xt, const float* __restrict__ G1, float c2,
    const float* __restrict__ o_part, const float* __restrict__ m_part,
    const float* __restrict__ l_part, float inv_sig,
    float* __restrict__ G2out, int nsplit)
{
    const int tid = threadIdx.x;
    const int w = tid >> 6, lane = tid & 63;
    const int row = blockIdx.x * 4 + w;
    float mstar = -1.0e30f;
    for (int i = 0; i < nsplit; ++i)
        mstar = fmaxf(mstar, m_part[i * N_ROWS + row]);
    float L = 0.f, num = 0.f;
    for (int i = 0; i < nsplit; ++i) {
        float e = __expf(m_part[i * N_ROWS + row] - mstar);
        L   += l_part[i * N_ROWS + row] * e;
        num += o_part[((size_t)i * N_ROWS + row) * DDIM + lane] * e;
    }
    const float qt = num / L;
    const size_t idx = (size_t)row * DDIM + lane;
    const float g1 = G1[idx];
    const float x  = xt[idx] + c2 * g1;
    const float g2 = ((1.0f - SIG0) * x - qt) * inv_sig;
    G2out[idx] = g2;
    xt[idx] -= (g1 + g2) * (HSTEP * 0.5f);
}

// ---------------------------------------------------------------------------
extern "C" void kernel_launch(void* const* d_in, const int* in_sizes, int n_in,
                              void* d_out, int out_size, void* d_ws, size_t ws_size,
                              hipStream_t stream) {
    const float* z  = (const float*)d_in[0];
    const float* x0 = (const float*)d_in[1];
    float* xt = (float*)d_out;

    // ---- workspace layout (256B aligned blocks) ----
    char* p = (char*)d_ws;
    auto alloc = [&](size_t bytes) {
        char* q = p; p += (bytes + 255) & ~(size_t)255; return q;
    };
    float*  G1    = (float*)alloc((size_t)N_ROWS * DDIM * 4);
    float*  G2    = (float*)alloc((size_t)N_ROWS * DDIM * 4);
    float*  x0sq  = (float*)alloc((size_t)N_ROWS * 4);
    float*  x0sum = (float*)alloc(64 * 4);
    short8* Apk_h = (short8*)alloc((size_t)NKB * 4 * 2 * 64 * 16);
    short8* Apk_l = (short8*)alloc((size_t)NKB * 4 * 2 * 64 * 16);
    short8* Bpk_h = (short8*)alloc((size_t)NKB * 2 * 4 * 64 * 16);
    short8* Bpk_l = (short8*)alloc((size_t)NKB * 2 * 4 * 64 * 16);
    size_t fixed = (size_t)(p - (char*)d_ws);
    const size_t per_split = ((size_t)N_ROWS * DDIM + 2 * N_ROWS) * 4 + 768;
    int SPLIT = 16;
    while (SPLIT > 1 && fixed + (size_t)SPLIT * per_split > ws_size) SPLIT >>= 1;
    float* o_part = (float*)alloc((size_t)SPLIT * N_ROWS * DDIM * 4);
    float* m_part = (float*)alloc((size_t)SPLIT * N_ROWS * 4);
    float* l_part = (float*)alloc((size_t)SPLIT * N_ROWS * 4);
    const int ntiles = NKB / SPLIT;

    // ---- init: xt = z; x0 derived arrays; G1 = G(t=1) closed form ----
    hipMemcpyAsync(xt, z, (size_t)N_ROWS * DDIM * 4, hipMemcpyDeviceToDevice, stream);
    hipMemsetAsync(x0sum, 0, 64 * 4, stream);
    x0stats_kernel<<<NKB, 256, 0, stream>>>(x0, x0sq, x0sum);
    prep_pack_kernel<<<NKB, 256, 0, stream>>>(x0, Apk_h, Apk_l, Bpk_h, Bpk_l);
    g1_init_kernel<<<(N_ROWS * DDIM) / 256, 256, 0, stream>>>(z, x0sum, G1);

    // ---- 7 Heun steps ----
    for (int i = 0; i < 7; ++i) {
        float t  = (float)(7 - i) / 8.0f;
        float al = 1.0f - t;
        float sg = SIG0 + (1.0f - SIG0) * t;
        float scale = al / (sg * sg);
        float beta  = al * al / (2.0f * sg * sg);
        g_partial_kernel<<<dim3(N_ROWS / 64, SPLIT), 256, 0, stream>>>(
            xt, G1, -HSTEP, Apk_h, Apk_l, Bpk_h, Bpk_l, x0sq, scale, beta,
            o_part, m_part, l_part, ntiles);
        combine_kernel<<<N_ROWS / 4, 256, 0, stream>>>(
            xt, G1, -HSTEP, o_part, m_part, l_part, 1.0f / sg, G2, SPLIT);
        float* tmp = G1; G1 = G2; G2 = tmp;
    }
}